// Round 8
// baseline (2837.520 us; speedup 1.0000x reference)
//
#include <hip/hip_runtime.h>
#include <hip/hip_bf16.h>
#include <cstdint>
#include <cstddef>

// LSTM encoder: B=64, T=512, D=256, UNITS=1024, gates G=4096 (i|f|g|o).
// R8: 8 logical machines of 32 WGs (machine = blockIdx>>5) as in R7, but the
// exchange is SELF-VALIDATING TAGGED DATA (R4 format, R7 staging):
//   h stored as 8B atomic chunks {2xbf16 | tag=t}, fire-and-forget -> the
//   store-ack RT and the flag RT are deleted. Consumer threads each own 128B
//   of the machine's tagged buffer, poll ONLY their own 8x16B until fresh
//   (per-thread retry, no ladder re-run -> R4's storm fixed), write 64B to
//   LDS, park at barrier. Poll loads ISSUED EARLY (before x@W) to hide RT.
// 2-buffer safety: store of h(t+1) requires consuming h(t) (syncthreads-gated)
// => all WGs consumed h(t-1) => overwrite safe (R4 argument, transitive).
// hlds layout [ks][quad][row^(ks&7)] -> ladder reads and staging writes are
// linear-equivalent (8 consecutive lanes hit 8 distinct bank groups).

#define SEQ_N  33554432    // 64*512*1024

typedef __attribute__((ext_vector_type(8))) short short8;
typedef __attribute__((ext_vector_type(4))) float floatx4;
typedef __attribute__((ext_vector_type(4))) int   intx4;
typedef __attribute__((ext_vector_type(2))) int   intx2;

#define BMFMA __builtin_amdgcn_mfma_f32_16x16x32_bf16

static __device__ __forceinline__ short f2bf(float f) {
  __hip_bfloat16 h = __float2bfloat16(f);
  return *reinterpret_cast<short*>(&h);
}
static __device__ __forceinline__ float sigm(float x) { return 1.f / (1.f + __expf(-x)); }
static __device__ __forceinline__ float tanh_fast(float x) {
  float xc = fminf(fmaxf(x, -15.f), 15.f);
  float e  = __expf(2.f * xc);
  return (e - 1.f) / (e + 1.f);
}

// ---- prep: pack [U;W] B-frags per unit-group ug (32 units), col-tile ct (4 units) ----
__global__ void pack_weights(const float* __restrict__ W, const float* __restrict__ U,
                             short* __restrict__ upack) {
  int idx  = blockIdx.x * 256 + threadIdx.x;   // 0 .. 655359
  int lane = idx & 63;
  int frag = idx >> 6;
  int kk   = frag % 40;
  int ct   = (frag / 40) & 7;
  int ug   = frag / 320;
  int quad = lane >> 4, n = lane & 15;
  int col  = (n >> 2) * 1024 + ug * 32 + ct * 4 + (n & 3);
  int k0   = kk * 32 + quad * 8;
  short8 v;
#pragma unroll
  for (int j = 0; j < 8; ++j) {
    int k = k0 + j;
    float f = (k < 1024) ? U[(size_t)k * 4096 + col] : W[(size_t)(k - 1024) * 4096 + col];
    v[j] = f2bf(f);
  }
  *reinterpret_cast<short8*>(upack + (size_t)idx * 8) = v;
}

__global__ void convert_x(const float* __restrict__ x, short* __restrict__ xbf) {
  int idx = blockIdx.x * 256 + threadIdx.x;
  const float* xp = x + (size_t)idx * 8;
  short8 v;
#pragma unroll
  for (int j = 0; j < 8; ++j) v[j] = f2bf(xp[j]);
  *reinterpret_cast<short8*>(xbf + (size_t)idx * 8) = v;
}

// hx: [8 mach][2 par][8 row][32 slot][16 chunks{data,tag}] = 512KB.
// buf0 = h(0): data 0, tag 0. buf1: tags = -1 (never matches). zb: 64B zeros.
__global__ void init_state(unsigned int* __restrict__ hx32) {
  int idx = blockIdx.x * 256 + threadIdx.x;   // 513 blocks
  if (idx < 131072) {
    int within = idx & 16383;                 // dword within one machine
    unsigned int v = 0u;
    if ((within >> 13) == 1 && (idx & 1)) v = 0xFFFFFFFFu;   // buf1 tag dwords
    __hip_atomic_store(&hx32[idx], v, __ATOMIC_RELAXED, __HIP_MEMORY_SCOPE_AGENT);
  } else if (idx < 131088) {
    __hip_atomic_store(&hx32[idx], 0u, __ATOMIC_RELAXED, __HIP_MEMORY_SCOPE_AGENT);
  }
}

// issue this thread's 8 tagged 16B loads (bypass, saddr form), NO wait.
#define ISSUE8(SB)                                                          \
  asm volatile(                                                             \
    "global_load_dwordx4 %0, %8, %16 sc0 sc1\n\t"                           \
    "global_load_dwordx4 %1, %9, %16 sc0 sc1\n\t"                           \
    "global_load_dwordx4 %2, %10, %16 sc0 sc1\n\t"                          \
    "global_load_dwordx4 %3, %11, %16 sc0 sc1\n\t"                          \
    "global_load_dwordx4 %4, %12, %16 sc0 sc1\n\t"                          \
    "global_load_dwordx4 %5, %13, %16 sc0 sc1\n\t"                          \
    "global_load_dwordx4 %6, %14, %16 sc0 sc1\n\t"                          \
    "global_load_dwordx4 %7, %15, %16 sc0 sc1"                              \
    : "=&v"(L0), "=&v"(L1), "=&v"(L2), "=&v"(L3),                           \
      "=&v"(L4), "=&v"(L5), "=&v"(L6), "=&v"(L7)                            \
    : "v"(vo0), "v"(vo1), "v"(vo2), "v"(vo3),                               \
      "v"(vo4), "v"(vo5), "v"(vo6), "v"(vo7), "s"(SB) : "memory")

// ---- persistent stepper: 256 WGs x 256 threads ----
__global__ __launch_bounds__(256, 1) void lstm_persist(
    const short* __restrict__ xbf,      // [64][512][256] bf16
    const short* __restrict__ upack,    // per-ug packed B frags
    const float* __restrict__ bias,     // [4096] f32
    char* __restrict__ hx,              // tagged h exchange buffers
    const short* __restrict__ zb,       // 64B zeros (x pad-row A-frags)
    float* __restrict__ out)
{
  __shared__ short hlds[16384];         // 32KB: [ks(32)][quad(4)][rowp(16)][8 units]
  __shared__ float zlds[8][8][17];      // 4.4KB gate staging

  const int m    = blockIdx.x >> 5;     // machine: rows [8m, 8m+8)
  const int slot = blockIdx.x & 31;     // unit group within machine
  const int ub   = slot * 32;

  const int tid  = threadIdx.x;
  const int wave = tid >> 6;
  const int lane = tid & 63;
  const int quad = lane >> 4;
  const int l15  = lane & 15;
  const int te   = 2 * wave, to = 2 * wave + 1;

  // elementwise / producer identity: thread -> (row, unit)
  const int erow = tid >> 5;            // 0..7
  const int us   = tid & 31;
  const int ui   = us & 3, ct_e = us >> 2;
  const int unit = ub + us;
  const float bi = bias[unit],        bfv = bias[1024 + unit];
  const float bg = bias[2048 + unit], bo  = bias[3072 + unit];
  float cst = 0.f;

  // ---- U-weights fully VGPR-resident ----
  const short* wbase = upack + (size_t)slot * (8 * 40 * 64 * 8);
  short8 wUe[32], wUo[32];
#pragma unroll
  for (int ks = 0; ks < 32; ++ks) {
    wUe[ks] = *reinterpret_cast<const short8*>(wbase + (((size_t)te * 40 + ks) * 64 + lane) * 8);
    wUo[ks] = *reinterpret_cast<const short8*>(wbase + (((size_t)to * 40 + ks) * 64 + lane) * 8);
  }
  {  // zero all of hlds once; pad rows (8..15) stay zero forever
    short8 z = {0, 0, 0, 0, 0, 0, 0, 0};
    for (int i = tid; i < 2048; i += 256)
      *reinterpret_cast<short8*>((char*)hlds + i * 16) = z;
  }
  __syncthreads();

  // x@W partials (B-frags from cached upack)
  floatx4 xe0, xe1, xo0, xo1;
  auto xw = [&](int t) {
    floatx4 z4 = {0.f, 0.f, 0.f, 0.f};
    floatx4 e0 = z4, e1 = z4, o0 = z4, o1 = z4;
    const short* xr = (l15 < 8)
        ? xbf + (((size_t)(8 * m + l15) * 512 + t) * 256 + quad * 8)
        : zb + quad * 8;
    const int xstep = (l15 < 8) ? 32 : 0;
    const short* wbe = wbase + (((size_t)te * 40 + 32) * 64 + lane) * 8;
    const short* wbo = wbase + (((size_t)to * 40 + 32) * 64 + lane) * 8;
#pragma unroll
    for (int ks = 0; ks < 8; ++ks) {
      short8 A  = *reinterpret_cast<const short8*>(xr); xr += xstep;
      short8 Be = *reinterpret_cast<const short8*>(wbe + ks * 512);
      short8 Bo = *reinterpret_cast<const short8*>(wbo + ks * 512);
      if (ks & 1) { e1 = BMFMA(A, Be, e1, 0, 0, 0); o1 = BMFMA(A, Bo, o1, 0, 0, 0); }
      else        { e0 = BMFMA(A, Be, e0, 0, 0, 0); o0 = BMFMA(A, Bo, o0, 0, 0, 0); }
    }
    xe0 = e0; xe1 = e1; xo0 = o0; xo1 = o1;
  };
  xw(0);

  // ---- tagged-exchange constants ----
  const unsigned long long sb0 = (unsigned long long)(hx + ((size_t)m << 16));
  const unsigned long long sb1 = sb0 + 32768ull;
  // consumer: piece j = 16B at byte tid*16 + j*4096 of the 32KB par-buffer
  const unsigned int vo0 = tid * 16,          vo1 = tid * 16 + 4096;
  const unsigned int vo2 = tid * 16 + 8192,   vo3 = tid * 16 + 12288;
  const unsigned int vo4 = tid * 16 + 16384,  vo5 = tid * 16 + 20480;
  const unsigned int vo6 = tid * 16 + 24576,  vo7 = tid * 16 + 28672;
  // LDS destination for piece j (4 units = 8B)
  char* db[8];
#pragma unroll
  for (int j = 0; j < 8; ++j) {
    int g     = tid * 16 + j * 4096;
    int seg   = g >> 7;                 // row*32 + slot
    int srow  = seg >> 5, sslot = seg & 31;
    int jj    = (g >> 4) & 7;
    db[j] = (char*)hlds + sslot * 1024 + (jj >> 1) * 256
          + ((srow ^ (sslot & 7)) << 4) + (jj & 1) * 8;
  }
  // producer: chunk (us>>1) of segment (erow, slot)
  char* pb = hx + ((size_t)m << 16) + (size_t)(erow * 32 + slot) * 128 + (us >> 1) * 8;

  intx4 L0, L1, L2, L3, L4, L5, L6, L7;
  ISSUE8(sb0);                          // prologue: h(0) tagged loads in flight

  for (int t = 0; t < 512; ++t) {
    const unsigned long long sbt = (t & 1) ? sb1 : sb0;
    // ---- poll own tagged pieces (fused flag+data; per-thread retry) ----
    {
      const int T = t;
      for (;;) {
        asm volatile("s_waitcnt vmcnt(0)" ::: "memory");
        __builtin_amdgcn_sched_barrier(0);        // rule 18: pin reads below
        int bad = (L0[1]^T)|(L0[3]^T)|(L1[1]^T)|(L1[3]^T)
                | (L2[1]^T)|(L2[3]^T)|(L3[1]^T)|(L3[3]^T)
                | (L4[1]^T)|(L4[3]^T)|(L5[1]^T)|(L5[3]^T)
                | (L6[1]^T)|(L6[3]^T)|(L7[1]^T)|(L7[3]^T);
        if (bad == 0) break;
        ISSUE8(sbt);
      }
      intx2 d0 = {L0[0], L0[2]}, d1 = {L1[0], L1[2]};
      intx2 d2 = {L2[0], L2[2]}, d3 = {L3[0], L3[2]};
      intx2 d4 = {L4[0], L4[2]}, d5 = {L5[0], L5[2]};
      intx2 d6 = {L6[0], L6[2]}, d7 = {L7[0], L7[2]};
      *reinterpret_cast<intx2*>(db[0]) = d0;
      *reinterpret_cast<intx2*>(db[1]) = d1;
      *reinterpret_cast<intx2*>(db[2]) = d2;
      *reinterpret_cast<intx2*>(db[3]) = d3;
      *reinterpret_cast<intx2*>(db[4]) = d4;
      *reinterpret_cast<intx2*>(db[5]) = d5;
      *reinterpret_cast<intx2*>(db[6]) = d6;
      *reinterpret_cast<intx2*>(db[7]) = d7;
    }
    __syncthreads();                    // h(t) fully staged in LDS

    // ---- h@U ladder: A from hlds [ks][quad][row^ks], U from VGPRs ----
    floatx4 aE0 = xe0, aE1 = xe1, aO0 = xo0, aO1 = xo1;
#pragma unroll
    for (int ks = 0; ks < 32; ++ks) {
      int rp = (l15 & 8) | ((l15 & 7) ^ (ks & 7));
      short8 A = *reinterpret_cast<const short8*>(
          (char*)hlds + ks * 1024 + quad * 256 + rp * 16);
      if (ks & 1) { aE1 = BMFMA(A, wUe[ks], aE1, 0, 0, 0); aO1 = BMFMA(A, wUo[ks], aO1, 0, 0, 0); }
      else        { aE0 = BMFMA(A, wUe[ks], aE0, 0, 0, 0); aO0 = BMFMA(A, wUo[ks], aO0, 0, 0, 0); }
    }
    floatx4 aE = aE0 + aE1, aO = aO0 + aO1;
    // ---- transpose to zlds (C: col=l15, row=quad*4+i; rows<8 real) ----
    if (quad < 2) {
#pragma unroll
      for (int i = 0; i < 4; ++i) {
        int row = quad * 4 + i;
        zlds[row][te][l15] = aE[i];
        zlds[row][to][l15] = aO[i];
      }
    }
    __syncthreads();
    // ---- elementwise ----
    float zi = zlds[erow][ct_e][0 + ui] + bi;
    float zf = zlds[erow][ct_e][4 + ui] + bfv;
    float zg = zlds[erow][ct_e][8 + ui] + bg;
    float zo = zlds[erow][ct_e][12 + ui] + bo;
    float ig = sigm(zi), fg = sigm(zf), gg = tanh_fast(zg), og = sigm(zo);
    cst = fg * cst + ig * gg;
    float hn = og * tanh_fast(cst);

    if (t < 511) {
      // fire-and-forget tagged store of h(t+1): {2xbf16 | tag t+1}
      float hn1 = __shfl_xor(hn, 1);
      unsigned int p01 = (unsigned int)(unsigned short)f2bf(hn) |
                         ((unsigned int)(unsigned short)f2bf(hn1) << 16);
      if ((us & 1) == 0) {
        unsigned long long v = (unsigned long long)p01 |
                               ((unsigned long long)(unsigned int)(t + 1) << 32);
        __hip_atomic_store((unsigned long long*)(pb + (((t + 1) & 1) << 15)), v,
                           __ATOMIC_RELAXED, __HIP_MEMORY_SCOPE_AGENT);
      }
      out[((size_t)(8 * m + erow) * 512 + t) * 1024 + unit] = hn;
      ISSUE8((t & 1) ? sb0 : sb1);      // early poll loads for h(t+1)
      xw(t + 1);                        // hide store flight + load RT
    } else {
      size_t gr = 8 * m + erow;
      out[(gr * 512 + 511) * 1024 + unit] = hn;
      out[(size_t)SEQ_N + gr * 1024 + unit] = hn;              // h_last
      out[(size_t)SEQ_N + 65536 + gr * 1024 + unit] = cst;     // c_last
    }
  }
}

extern "C" void kernel_launch(void* const* d_in, const int* in_sizes, int n_in,
                              void* d_out, int out_size, void* d_ws, size_t ws_size,
                              hipStream_t stream) {
  const float* x    = (const float*)d_in[0];
  const float* W    = (const float*)d_in[1];
  const float* U    = (const float*)d_in[2];
  const float* bias = (const float*)d_in[3];
  float* out = (float*)d_out;
  char* ws = (char*)d_ws;

  short* upack = (short*)ws;                       // 10,485,760 B
  short* xbf   = (short*)(ws + 10485760);          // 16,777,216 B
  char*  hx    = ws + 27262976;                    //    524,288 B
  short* zb    = (short*)(ws + 27787264);          //         64 B
  (void)in_sizes; (void)n_in; (void)out_size; (void)ws_size;

  init_state<<<513, 256, 0, stream>>>((unsigned int*)hx);
  pack_weights<<<2560, 256, 0, stream>>>(W, U, upack);
  convert_x<<<4096, 256, 0, stream>>>(x, xbf);
  lstm_persist<<<256, 256, 0, stream>>>(xbf, upack, bias, hx, zb, out);
}

// Round 9
// 2456.610 us; speedup vs baseline: 1.1551x; 1.1551x over previous
//
#include <hip/hip_runtime.h>
#include <hip/hip_bf16.h>
#include <cstdint>
#include <cstddef>

// LSTM encoder: B=64, T=512, D=256, UNITS=1024, gates G=4096 (i|f|g|o).
// R9 = R7 structure with the h-exchange moved to the XCD-local L2, plus a
// sticky MALL fallback:
//  - machine = physical XCD via asm `hwreg(HW_REG_XCC_ID)` (m09-proven name;
//    R6's raw id-20 was FLAT_SCR_LO -> garbage -> deadlock).
//  - 384 WGs; per-XCD atomic claim; slot>=32 exits (R5's no-slack bug fixed).
//  - producers DUAL-STORE h (sc0 local L2 + sc0 sc1 MALL, same value) and
//    dual-flag: vmcnt(1) (sc0 acked, in-order retire) -> fast-flag sc0;
//    vmcnt(0) (sc1 acked) -> slow-flag sc0 sc1.
//  - consumers fast-poll sc0 flags with timeout -> STICKY fallback to the
//    MALL path (≈R7 perf). Deadlock-free by construction.
// Within one XCD there is a single L2 -> relaxed sc0 store->load visibility is
// sound; machines are 32KB-aligned (no cross-machine line sharing). Everything
// else (staging swizzle, ladder, elementwise, 2-buffer safety) = R7 verbatim.

#define SEQ_N  33554432    // 64*512*1024

typedef __attribute__((ext_vector_type(8))) short short8;
typedef __attribute__((ext_vector_type(4))) float floatx4;

#define BMFMA __builtin_amdgcn_mfma_f32_16x16x32_bf16

static __device__ __forceinline__ short f2bf(float f) {
  __hip_bfloat16 h = __float2bfloat16(f);
  return *reinterpret_cast<short*>(&h);
}
static __device__ __forceinline__ float sigm(float x) { return 1.f / (1.f + __expf(-x)); }
static __device__ __forceinline__ float tanh_fast(float x) {
  float xc = fminf(fmaxf(x, -15.f), 15.f);
  float e  = __expf(2.f * xc);
  return (e - 1.f) / (e + 1.f);
}

// ---- prep: pack [U;W] B-frags per unit-group ug (32 units), col-tile ct (4 units) ----
// upack[ug(32)][ct(8)][kk(40)][lane(64)][8 shorts]
__global__ void pack_weights(const float* __restrict__ W, const float* __restrict__ U,
                             short* __restrict__ upack) {
  int idx  = blockIdx.x * 256 + threadIdx.x;   // 0 .. 655359
  int lane = idx & 63;
  int frag = idx >> 6;
  int kk   = frag % 40;
  int ct   = (frag / 40) & 7;
  int ug   = frag / 320;
  int quad = lane >> 4, n = lane & 15;
  int col  = (n >> 2) * 1024 + ug * 32 + ct * 4 + (n & 3);
  int k0   = kk * 32 + quad * 8;
  short8 v;
#pragma unroll
  for (int j = 0; j < 8; ++j) {
    int k = k0 + j;
    float f = (k < 1024) ? U[(size_t)k * 4096 + col] : W[(size_t)(k - 1024) * 4096 + col];
    v[j] = f2bf(f);
  }
  *reinterpret_cast<short8*>(upack + (size_t)idx * 8) = v;
}

__global__ void convert_x(const float* __restrict__ x, short* __restrict__ xbf) {
  int idx = blockIdx.x * 256 + threadIdx.x;
  const float* xp = x + (size_t)idx * 8;
  short8 v;
#pragma unroll
  for (int j = 0; j < 8; ++j) v[j] = f2bf(xp[j]);
  *reinterpret_cast<short8*>(xbf + (size_t)idx * 8) = v;
}

// zero hx + fastf + slowf + ctr + zb at the device coherence point.
__global__ void init_state(unsigned int* __restrict__ base) {
  int idx = blockIdx.x * 256 + threadIdx.x;    // 259 blocks
  if (idx < 66192)
    __hip_atomic_store(&base[idx], 0u, __ATOMIC_RELAXED, __HIP_MEMORY_SCOPE_AGENT);
}

// ---- persistent stepper: 384 WGs x 256 threads; 32 workers/XCD, extras exit ----
__global__ __launch_bounds__(256, 1) void lstm_persist(
    const short* __restrict__ xbf,      // [64][512][256] bf16
    const short* __restrict__ upack,    // per-ug packed B frags
    const float* __restrict__ bias,     // [4096] f32
    char* __restrict__ hx,              // [8 mach][2 par][8 rows][1024] bf16
    int* __restrict__ fastf,            // [8 mach][32] flags (sc0 / L2)
    int* __restrict__ slowf,            // [8 mach][32] flags (sc1 / MALL)
    int* __restrict__ ctr,              // [8 mach] @64B stride
    const short* __restrict__ zb,       // 64B zeros (x pad-row A-frags)
    float* __restrict__ out)
{
  __shared__ short hlds[16384];         // 32KB: 16 padded rows x 1024 bf16 (swizzled)
  __shared__ float zlds[8][8][17];      // 4.4KB gate staging
  __shared__ int   slot_sh;
  __shared__ int   use_slow_sh;

  int xcd;
  asm volatile("s_getreg_b32 %0, hwreg(HW_REG_XCC_ID)" : "=s"(xcd));
  const int m   = xcd & 7;              // machine = physical XCD: rows [8m, 8m+8)
  const int tid = threadIdx.x;

  if (tid == 0) {
    slot_sh = __hip_atomic_fetch_add(&ctr[m * 16], 1,
                                     __ATOMIC_RELAXED, __HIP_MEMORY_SCOPE_AGENT);
    use_slow_sh = 0;
  }
  __syncthreads();
  const int slot = slot_sh;
  if (slot >= 32) return;               // over-provisioned extra: exit
  const int ub   = slot * 32;           // first unit owned by this WG

  const int wave = tid >> 6;
  const int lane = tid & 63;
  const int quad = lane >> 4;
  const int l15  = lane & 15;
  const int te   = 2 * wave, to = 2 * wave + 1;   // this wave's col-tiles

  // elementwise identity: thread -> (row, unit)
  const int erow = tid >> 5;            // 0..7 local row
  const int us   = tid & 31;
  const int ui   = us & 3, ct_e = us >> 2;
  const int unit = ub + us;
  const float bi = bias[unit],        bfv = bias[1024 + unit];
  const float bg = bias[2048 + unit], bo  = bias[3072 + unit];
  float cst = 0.f;

  // ---- U-weights VGPR-resident ----
  const short* wbase = upack + (size_t)slot * (8 * 40 * 64 * 8);
  short8 wUe[32], wUo[32];
#pragma unroll
  for (int ks = 0; ks < 32; ++ks) {
    wUe[ks] = *reinterpret_cast<const short8*>(wbase + (((size_t)te * 40 + ks) * 64 + lane) * 8);
    wUo[ks] = *reinterpret_cast<const short8*>(wbase + (((size_t)to * 40 + ks) * 64 + lane) * 8);
  }
  {  // zero hlds pad rows 8..15
    int r = 8 + (tid >> 5), seg = tid & 31;
    short8 z = {0, 0, 0, 0, 0, 0, 0, 0};
    const int sw = (r & 7) << 4;
#pragma unroll
    for (int j = 0; j < 4; ++j) {
      int b = seg * 16 + j * 512;
      *reinterpret_cast<short8*>((char*)hlds + r * 2048 + (b ^ sw)) = z;
    }
  }
  __syncthreads();

  // x@W partials (B-frags from cached upack)
  floatx4 xe0, xe1, xo0, xo1;
  auto xw = [&](int t) {
    floatx4 z4 = {0.f, 0.f, 0.f, 0.f};
    floatx4 e0 = z4, e1 = z4, o0 = z4, o1 = z4;
    const short* xr = (l15 < 8)
        ? xbf + (((size_t)(8 * m + l15) * 512 + t) * 256 + quad * 8)
        : zb + quad * 8;
    const int xstep = (l15 < 8) ? 32 : 0;
    const short* wbe = wbase + (((size_t)te * 40 + 32) * 64 + lane) * 8;
    const short* wbo = wbase + (((size_t)to * 40 + 32) * 64 + lane) * 8;
#pragma unroll
    for (int ks = 0; ks < 8; ++ks) {
      short8 A  = *reinterpret_cast<const short8*>(xr); xr += xstep;
      short8 Be = *reinterpret_cast<const short8*>(wbe + ks * 512);
      short8 Bo = *reinterpret_cast<const short8*>(wbo + ks * 512);
      if (ks & 1) { e1 = BMFMA(A, Be, e1, 0, 0, 0); o1 = BMFMA(A, Bo, o1, 0, 0, 0); }
      else        { e0 = BMFMA(A, Be, e0, 0, 0, 0); o0 = BMFMA(A, Bo, o0, 0, 0, 0); }
    }
    xe0 = e0; xe1 = e1; xo0 = o0; xo1 = o1;
  };
  xw(0);

  const int stage_r = tid >> 5, stage_seg = tid & 31;
  int* ffp = fastf + m * 32 + (lane & 31);
  int* sfp = slowf + m * 32 + (lane & 31);
  int* ffs = fastf + m * 32 + slot;
  int* sfs = slowf + m * 32 + slot;

  for (int t = 0; t < 512; ++t) {
    // 1. poll: fast (sc0/L2) with sticky timeout fallback to slow (MALL)
    if (t > 0) {
      if (wave == 0) {
        int uslow = use_slow_sh;
        if (!uslow) {
          int cnt = 0;
          for (;;) {
            int v;
            asm volatile("global_load_dword %0, %1, off sc0\n\t"
                         "s_waitcnt vmcnt(0)"
                         : "=v"(v) : "v"(ffp) : "memory");
            if (__all(v >= t)) break;
            if (++cnt > 8192) { uslow = 1; break; }
          }
          if (uslow && lane == 0) use_slow_sh = 1;    // sticky
        }
        if (uslow) {
          for (;;) {
            int v;
            asm volatile("global_load_dword %0, %1, off sc0 sc1\n\t"
                         "s_waitcnt vmcnt(0)"
                         : "=v"(v) : "v"(sfp) : "memory");
            if (__all(v >= t)) break;
          }
        }
      }
      __syncthreads();
    }
    // 2. stage h(t) (16KB) into swizzled LDS; scope matches the active path
    {
      const char* src = hx + ((size_t)(m * 2 + (t & 1)) << 14)
                      + stage_r * 2048 + stage_seg * 16;
      short8 v0, v1, v2, v3;
      if (!use_slow_sh) {
        asm volatile("global_load_dwordx4 %0, %4, off sc0\n\t"
                     "global_load_dwordx4 %1, %4, off offset:512 sc0\n\t"
                     "global_load_dwordx4 %2, %4, off offset:1024 sc0\n\t"
                     "global_load_dwordx4 %3, %4, off offset:1536 sc0\n\t"
                     "s_waitcnt vmcnt(0)"
                     : "=&v"(v0), "=&v"(v1), "=&v"(v2), "=&v"(v3)
                     : "v"(src) : "memory");
      } else {
        asm volatile("global_load_dwordx4 %0, %4, off sc0 sc1\n\t"
                     "global_load_dwordx4 %1, %4, off offset:512 sc0 sc1\n\t"
                     "global_load_dwordx4 %2, %4, off offset:1024 sc0 sc1\n\t"
                     "global_load_dwordx4 %3, %4, off offset:1536 sc0 sc1\n\t"
                     "s_waitcnt vmcnt(0)"
                     : "=&v"(v0), "=&v"(v1), "=&v"(v2), "=&v"(v3)
                     : "v"(src) : "memory");
      }
      char* dbase = (char*)hlds + stage_r * 2048;
      const int sw = (stage_r & 7) << 4;
      const int b0 = stage_seg * 16;
      *reinterpret_cast<short8*>(dbase + ((b0       ) ^ sw)) = v0;
      *reinterpret_cast<short8*>(dbase + ((b0 +  512) ^ sw)) = v1;
      *reinterpret_cast<short8*>(dbase + ((b0 + 1024) ^ sw)) = v2;
      *reinterpret_cast<short8*>(dbase + ((b0 + 1536) ^ sw)) = v3;
    }
    __syncthreads();
    // 3. h@U ladder: A from swizzled LDS, U-weights from VGPRs
    floatx4 aE0 = xe0, aE1 = xe1, aO0 = xo0, aO1 = xo1;
    {
      const char* hb = (const char*)hlds + l15 * 2048;
      const int rx = (l15 & 7) << 4;
#pragma unroll
      for (int ks = 0; ks < 32; ++ks) {
        short8 A = *reinterpret_cast<const short8*>(hb + ((ks * 64 + quad * 16) ^ rx));
        if (ks & 1) { aE1 = BMFMA(A, wUe[ks], aE1, 0, 0, 0); aO1 = BMFMA(A, wUo[ks], aO1, 0, 0, 0); }
        else        { aE0 = BMFMA(A, wUe[ks], aE0, 0, 0, 0); aO0 = BMFMA(A, wUo[ks], aO0, 0, 0, 0); }
      }
    }
    floatx4 aE = aE0 + aE1, aO = aO0 + aO1;
    // 4. transpose to zlds
    if (quad < 2) {
#pragma unroll
      for (int i = 0; i < 4; ++i) {
        int row = quad * 4 + i;
        zlds[row][te][l15] = aE[i];
        zlds[row][to][l15] = aO[i];
      }
    }
    __syncthreads();
    // 5. elementwise
    float zi = zlds[erow][ct_e][0 + ui] + bi;
    float zf = zlds[erow][ct_e][4 + ui] + bfv;
    float zg = zlds[erow][ct_e][8 + ui] + bg;
    float zo = zlds[erow][ct_e][12 + ui] + bo;
    float ig = sigm(zi), fg = sigm(zf), gg = tanh_fast(zg), og = sigm(zo);
    cst = fg * cst + ig * gg;
    float hn = og * tanh_fast(cst);

    if (t < 511) {
      // 6. dual-store h(t+1): sc0 (local L2) + sc0 sc1 (MALL), same value
      float hn1 = __shfl_xor(hn, 1);
      unsigned int p01 = (unsigned int)(unsigned short)f2bf(hn) |
                         ((unsigned int)(unsigned short)f2bf(hn1) << 16);
      unsigned int pot = __shfl_xor(p01, 2);
      if (ui == 0) {
        unsigned long long v = (unsigned long long)p01 |
                               ((unsigned long long)pot << 32);
        char* dst = hx + ((size_t)(m * 2 + ((t + 1) & 1)) << 14)
                  + erow * 2048 + (size_t)(ub + (us & ~3)) * 2;
        asm volatile("global_store_dwordx2 %0, %1, off sc0\n\t"
                     "global_store_dwordx2 %0, %1, off sc0 sc1"
                     :: "v"(dst), "v"(v) : "memory");
      }
      // sc0 store acked (in-order vmcnt retire; sc1 may still fly)
      asm volatile("s_waitcnt vmcnt(1)" ::: "memory");
      __syncthreads();
      int tv = t + 1;
      if (tid == 0)
        asm volatile("global_store_dword %0, %1, off sc0" :: "v"(ffs), "v"(tv) : "memory");
      out[((size_t)(8 * m + erow) * 512 + t) * 1024 + unit] = hn;
      xw(t + 1);                                   // hides flag flight
      asm volatile("s_waitcnt vmcnt(0)" ::: "memory");   // sc1 data acked
      __syncthreads();
      if (tid == 0)
        asm volatile("global_store_dword %0, %1, off sc0 sc1" :: "v"(sfs), "v"(tv) : "memory");
    } else {
      size_t gr = 8 * m + erow;
      out[(gr * 512 + 511) * 1024 + unit] = hn;
      out[(size_t)SEQ_N + gr * 1024 + unit] = hn;              // h_last
      out[(size_t)SEQ_N + 65536 + gr * 1024 + unit] = cst;     // c_last
    }
  }
}

extern "C" void kernel_launch(void* const* d_in, const int* in_sizes, int n_in,
                              void* d_out, int out_size, void* d_ws, size_t ws_size,
                              hipStream_t stream) {
  const float* x    = (const float*)d_in[0];
  const float* W    = (const float*)d_in[1];
  const float* U    = (const float*)d_in[2];
  const float* bias = (const float*)d_in[3];
  float* out = (float*)d_out;
  char* ws = (char*)d_ws;

  short* upack = (short*)ws;                       // 10,485,760 B
  short* xbf   = (short*)(ws + 10485760);          // 16,777,216 B
  char*  hx    = ws + 27262976;                    //    262,144 B (32KB-aligned/machine)
  int*   fastf = (int*)(ws + 27525120);            //      1,024 B
  int*   slowf = (int*)(ws + 27526144);            //      1,024 B
  int*   ctr   = (int*)(ws + 27527168);            //        512 B
  short* zb    = (short*)(ws + 27527680);          //         64 B
  (void)in_sizes; (void)n_in; (void)out_size; (void)ws_size;

  init_state<<<259, 256, 0, stream>>>((unsigned int*)(ws + 27262976));
  pack_weights<<<2560, 256, 0, stream>>>(W, U, upack);
  convert_x<<<4096, 256, 0, stream>>>(x, xbf);
  lstm_persist<<<384, 256, 0, stream>>>(xbf, upack, bias, hx, fastf, slowf, ctr, zb, out);
}